// Round 17
// baseline (26.799 us; speedup 1.0000x reference)
//
#include <hip/hip_runtime.h>
#include <hip/hip_bf16.h>
#include <math.h>

// Problem constants
#define BS_    512
#define NA_    10
#define NE_    11
#define NAL_   9
#define H_     64
#define HEADS_ 4
#define EDIM_  8
#define ADIM_  8
#define OWN_   14
#define HYP_   64
#define NTOT_  (BS_*NA_)   // 5120
#define AGB_   16          // agents per block (16 MFMA rows fully used)

// ws layout (unchanged from R14):
#define WGRU_US   67584
#define WVV_US    100352
#define WFC2_US   104448
#define WB_OFF    52736     // [64]
#define B4_OFF    52800     // [256]
#define FB_OFF    53056     // [16]
#define WS_FLOATS 53072

typedef __attribute__((ext_vector_type(8))) short short8_t;
typedef __attribute__((ext_vector_type(4))) float f32x4;

__device__ __forceinline__ unsigned short to_bf16(float v) {
    unsigned u = __float_as_uint(v);
    u += 0x7fffu + ((u >> 16) & 1u);
    return (unsigned short)(u >> 16);
}
__device__ __forceinline__ unsigned pack2(float lo, float hi) {
    return ((unsigned)to_bf16(hi) << 16) | to_bf16(lo);
}

__global__ __launch_bounds__(256) void prep_kernel(
    const float* __restrict__ fc1_own_w, const float* __restrict__ fc1_own_b,
    const float* __restrict__ he_w2, const float* __restrict__ he_b2,
    const float* __restrict__ ha_w2, const float* __restrict__ ha_b2,
    const float* __restrict__ merge_in_w,
    const float* __restrict__ gru_w_ih, const float* __restrict__ gru_w_hh,
    const float* __restrict__ gru_b_ih, const float* __restrict__ gru_b_hh,
    const float* __restrict__ merge_out_w,
    const float* __restrict__ fc2_w, const float* __restrict__ fc2_b,
    float* __restrict__ ws)
{
    const int tid = blockIdx.x * blockDim.x + threadIdx.x;

    float wo0, wo1, wo2, wo3;
    {
        float e0 = expf(merge_out_w[0]), e1 = expf(merge_out_w[1]);
        float e2 = expf(merge_out_w[2]), e3 = expf(merge_out_w[3]);
        float inv = 1.0f / (e0 + e1 + e2 + e3);
        wo0 = e0*inv; wo1 = e1*inv; wo2 = e2*inv; wo3 = e3*inv;
    }

    if (tid < 65536) {
        const int half = tid >> 15;
        const int t    = tid & 32767;
        const int col  = t >> 9;
        const int idxL = t & 511;
        const int e    = idxL >> 6;
        const int kk   = idxL & 63;
        const float e0 = expf(merge_in_w[col]),       e1 = expf(merge_in_w[64 + col]);
        const float e2 = expf(merge_in_w[128 + col]), e3 = expf(merge_in_w[192 + col]);
        const float inv = 1.0f / (e0 + e1 + e2 + e3);
        const float wi[4] = { e0*inv, e1*inv, e2*inv, e3*inv };
        const float* Wsrc = half ? ha_w2 : he_w2;
        float v = 0.f;
#pragma unroll
        for (int hd = 0; hd < 4; hd++)
            v += wi[hd] * Wsrc[(size_t)(e*256 + hd*64 + col)*64 + kk];
        const int k   = half*512 + kk*8 + e;
        const int ks  = k >> 5, sub = k & 31;
        const int outp = (col >> 4)*16896 + ks*512 + (((sub >> 3) << 4) + (col & 15))*8 + (sub & 7);
        ((unsigned short*)ws)[outp] = to_bf16(v);
    } else if (tid < 67584) {
        const int t   = tid - 65536;
        const int col = t >> 5;
        const int io  = t & 31;
        float v = 0.f;
        if (io < 16) {
            const float e0 = expf(merge_in_w[col]),       e1 = expf(merge_in_w[64 + col]);
            const float e2 = expf(merge_in_w[128 + col]), e3 = expf(merge_in_w[192 + col]);
            const float inv = 1.0f / (e0 + e1 + e2 + e3);
            const float wi[4] = { e0*inv, e1*inv, e2*inv, e3*inv };
            const float* Bsrc = (io < 8) ? he_b2 : ha_b2;
            const int e = io & 7;
#pragma unroll
            for (int hd = 0; hd < 4; hd++)
                v += wi[hd] * Bsrc[e*256 + hd*64 + col];
        } else if (io < 30) {
            v = fc1_own_w[col*OWN_ + (io - 16)];
        } else if (io == 30) {
            v = fc1_own_b[col];
        }
        const int outp = (col >> 4)*16896 + 32*512 + (((io >> 3) << 4) + (col & 15))*8 + (io & 7);
        ((unsigned short*)ws)[outp] = to_bf16(v);
    } else if (tid < 100352) {
        const int t = tid - 67584;
        const int j  = t & 7;
        const int fl = (t >> 3) & 63;
        const int kstep = (t >> 9) & 3;
        const int T  = t >> 11;
        const int k  = kstep*32 + ((fl >> 4) << 3) + j;
        const int kk = k >> 1;
        const bool hside = (k & 1);
        const int c  = T*16 + (fl & 15);
        const int g  = c >> 6;
        const int u  = c & 63;
        float v;
        if (g == 0)      v = hside ? gru_w_hh[u*64 + kk]       : gru_w_ih[u*64 + kk];
        else if (g == 1) v = hside ? gru_w_hh[(64+u)*64 + kk]  : gru_w_ih[(64+u)*64 + kk];
        else if (g == 2) v = hside ? 0.f                        : gru_w_ih[(128+u)*64 + kk];
        else             v = hside ? gru_w_hh[(128+u)*64 + kk] : 0.f;
        ((unsigned short*)ws)[WGRU_US + t] = to_bf16(v);
    } else if (tid < 104448) {
        const int t = tid - 100352;
        const int j  = t & 7;
        const int fl = (t >> 3) & 63;
        const int kstep = (t >> 9) & 1;
        const int nt = t >> 10;
        const int k  = kstep*32 + ((fl >> 4) << 3) + j;
        const int col = nt*16 + (fl & 15);
        float v = wo0 * he_w2[(2048 + 0*64 + k)*64 + col]
                + wo1 * he_w2[(2048 + 1*64 + k)*64 + col]
                + wo2 * he_w2[(2048 + 2*64 + k)*64 + col]
                + wo3 * he_w2[(2048 + 3*64 + k)*64 + col];
        ((unsigned short*)ws)[WVV_US + t] = to_bf16(v);
    } else if (tid < 105472) {
        const int t = tid - 104448;
        const int j  = t & 7;
        const int fl = (t >> 3) & 63;
        const int kstep = t >> 9;
        const int k  = kstep*32 + ((fl >> 4) << 3) + j;
        const int col = fl & 15;
        float v = 0.f;
        if (col < 6)       v = fc2_w[col*64 + k];
        else if (col == 6) v = wo0*he_b2[2048 + 0*64 + k] + wo1*he_b2[2048 + 1*64 + k]
                             + wo2*he_b2[2048 + 2*64 + k] + wo3*he_b2[2048 + 3*64 + k];
        ((unsigned short*)ws)[WFC2_US + t] = to_bf16(v);
    } else if (tid < 105536) {
        const int k = tid - 105472;
        float v = wo0*he_w2[(2304+0)*64 + k] + wo1*he_w2[(2304+1)*64 + k]
                + wo2*he_w2[(2304+2)*64 + k] + wo3*he_w2[(2304+3)*64 + k];
        ws[WB_OFF + k] = v;
    } else if (tid < 105792) {
        const int c = tid - 105536;
        const int g = c >> 6, u = c & 63;
        float v;
        if (g == 0)      v = gru_b_ih[u]       + gru_b_hh[u];
        else if (g == 1) v = gru_b_ih[64 + u]  + gru_b_hh[64 + u];
        else if (g == 2) v = gru_b_ih[128 + u];
        else             v = gru_b_hh[128 + u];
        ws[B4_OFF + c] = v;
    } else if (tid < 105808) {
        const int col = tid - 105792;
        float v = 0.f;
        if (col < 6)       v = fc2_b[col];
        else if (col == 6) v = wo0*he_b2[2304] + wo1*he_b2[2305] + wo2*he_b2[2306] + wo3*he_b2[2307];
        ws[FB_OFF + col] = v;
    }
}

// LDS stage layout (floats): enemy [0,1408) ally [1408,2560) hidden [2560,3584) own [3584,3808)
#define STG_ALLY 1408
#define STG_HID  2560
#define STG_OWN  3584

// a_cmp row stride 1064 us (conflict-free b128 A-reads)
#define AROW_ 1064

__global__ __launch_bounds__(1024, 8) void main_kernel(
    const float* __restrict__ own_feats,
    const float* __restrict__ enemy_feats,
    const float* __restrict__ ally_feats,
    const float* __restrict__ hidden_state,
    const int*   __restrict__ agent_idx,
    const int*   __restrict__ last_act,
    const float* __restrict__ agent_emb,
    const float* __restrict__ action_emb,
    const float* __restrict__ he_w1,
    const float* __restrict__ he_b1,
    const float* __restrict__ ha_w1,
    const float* __restrict__ ha_b1,
    const float* __restrict__ ws,
    float* __restrict__ out)
{
    const int tid  = threadIdx.x;
    const int w    = tid >> 6;        // wave id 0..15 == agent slot
    const int lane = tid & 63;
    const int n    = blockIdx.x * AGB_ + w;
    const unsigned short* ws_us = (const unsigned short*)ws;

    __shared__ __align__(16) unsigned short a_cmp[AGB_][AROW_]; // 34048 B
    // scratch: stage [0,3808) persists whole kernel; pm/Gm union at +3808 (4160 floats)
    __shared__ __align__(16) float scratch[7968];               // 31872 B
    float* const stg = scratch;
    float* const pm  = scratch + 3808;      // pembM[4][16][64] = 4096
    float* const GmF = scratch + 3808;      // Gm[16][260] = 4160 (after pm dead)

    const int ai_r = agent_idx[n];
    const int la_r = last_act[n];

    // ============ Phase 0: cooperative input staging ========================
    {
        const int n0 = blockIdx.x * AGB_;
        const float4* src = nullptr;
        float* dst = nullptr;
        if (tid < 352)      { src = (const float4*)(enemy_feats + (size_t)n0*88) + tid;         dst = stg + tid*4; }
        else if (tid < 640) { src = (const float4*)(ally_feats + (size_t)n0*72) + (tid-352);    dst = stg + STG_ALLY + (tid-352)*4; }
        else if (tid < 896) { src = (const float4*)(hidden_state + (size_t)n0*64) + (tid-640);  dst = stg + STG_HID + (tid-640)*4; }
        else if (tid < 952) { src = (const float4*)(own_feats + (size_t)n0*14) + (tid-896);     dst = stg + STG_OWN + (tid-896)*4; }
        if (src) *(float4*)dst = *src;
    }
    __syncthreads();

    // ================= Phase 1: per-agent activations (wave = agent) ========
    float embo, hin_reg;
    {
        const float4 w1a  = *(const float4*)(he_w1 + lane*8);
        const float4 w1b  = *(const float4*)(he_w1 + lane*8 + 4);
        const float  hb1  = he_b1[lane];
        const float* se = stg + w*88;

        float ps[8] = {0,0,0,0,0,0,0,0};
#pragma unroll
        for (int ei = 0; ei < NE_; ei++) {
            const float4 e0 = *(const float4*)(se + ei*8);
            const float4 e1 = *(const float4*)(se + ei*8 + 4);
            float h = hb1;
            h = fmaf(e0.x, w1a.x, h); h = fmaf(e0.y, w1a.y, h);
            h = fmaf(e0.z, w1a.z, h); h = fmaf(e0.w, w1a.w, h);
            h = fmaf(e1.x, w1b.x, h); h = fmaf(e1.y, w1b.y, h);
            h = fmaf(e1.z, w1b.z, h); h = fmaf(e1.w, w1b.w, h);
            h = fmaxf(h, 0.f);
            ps[0] = fmaf(e0.x, h, ps[0]); ps[1] = fmaf(e0.y, h, ps[1]);
            ps[2] = fmaf(e0.z, h, ps[2]); ps[3] = fmaf(e0.w, h, ps[3]);
            ps[4] = fmaf(e1.x, h, ps[4]); ps[5] = fmaf(e1.y, h, ps[5]);
            ps[6] = fmaf(e1.z, h, ps[6]); ps[7] = fmaf(e1.w, h, ps[7]);
        }
        {
            uint4 pk;
            pk.x = pack2(ps[0], ps[1]); pk.y = pack2(ps[2], ps[3]);
            pk.z = pack2(ps[4], ps[5]); pk.w = pack2(ps[6], ps[7]);
            *(uint4*)&a_cmp[w][lane*8] = pk;
        }

        const float4 wa1a = *(const float4*)(ha_w1 + lane*8);
        const float4 wa1b = *(const float4*)(ha_w1 + lane*8 + 4);
        const float  hba1 = ha_b1[lane];
        const float* sa = stg + STG_ALLY + w*72;
        float pa[8] = {0,0,0,0,0,0,0,0};
#pragma unroll
        for (int ai = 0; ai < NAL_; ai++) {
            const float4 a0 = *(const float4*)(sa + ai*8);
            const float4 a1 = *(const float4*)(sa + ai*8 + 4);
            float h = hba1;
            h = fmaf(a0.x, wa1a.x, h); h = fmaf(a0.y, wa1a.y, h);
            h = fmaf(a0.z, wa1a.z, h); h = fmaf(a0.w, wa1a.w, h);
            h = fmaf(a1.x, wa1b.x, h); h = fmaf(a1.y, wa1b.y, h);
            h = fmaf(a1.z, wa1b.z, h); h = fmaf(a1.w, wa1b.w, h);
            h = fmaxf(h, 0.f);
            pa[0] = fmaf(a0.x, h, pa[0]); pa[1] = fmaf(a0.y, h, pa[1]);
            pa[2] = fmaf(a0.z, h, pa[2]); pa[3] = fmaf(a0.w, h, pa[3]);
            pa[4] = fmaf(a1.x, h, pa[4]); pa[5] = fmaf(a1.y, h, pa[5]);
            pa[6] = fmaf(a1.z, h, pa[6]); pa[7] = fmaf(a1.w, h, pa[7]);
        }
        {
            uint4 pk;
            pk.x = pack2(pa[0], pa[1]); pk.y = pack2(pa[2], pa[3]);
            pk.z = pack2(pa[4], pa[5]); pk.w = pack2(pa[6], pa[7]);
            *(uint4*)&a_cmp[w][512 + lane*8] = pk;
        }

        if (lane < 8) {
            float s = 0.f;
            for (int ei = 0; ei < NE_; ei++) s += se[ei*8 + lane];
            a_cmp[w][1024 + lane] = to_bf16(s);
        } else if (lane < 16) {
            const int p = lane - 8;
            float s = 0.f;
            for (int ai = 0; ai < NAL_; ai++) s += sa[ai*8 + p];
            a_cmp[w][1032 + p] = to_bf16(s);
        } else if (lane < 32) {
            float v;
            if (lane < 30)       v = stg[STG_OWN + w*OWN_ + (lane - 16)];
            else if (lane == 30) v = 1.f;
            else                 v = 0.f;
            a_cmp[w][1024 + lane] = to_bf16(v);
        }

        embo = agent_emb[ai_r*64 + lane] + action_emb[la_r*64 + lane];
        hin_reg = stg[STG_HID + (w << 6) + lane];
    }
    __syncthreads();

    // ====== Phase 2: MFMA emb[16x64] = A[16x1056]*W, wave=(quad, Kquarter) ==
    {
        const int q  = w & 3;
        const int kh = w >> 2;                 // 0..3
        const int ksa = kh ? (8*kh + 1) : 0;   // 9/8/8/8 split of 33
        const int ksb = 8*kh + 9;
        f32x4 acc0 = {0.f, 0.f, 0.f, 0.f};
        f32x4 acc1 = {0.f, 0.f, 0.f, 0.f};
        const unsigned short* wpw = ws_us + ((q * 33) << 9);
        const unsigned short* arow = &a_cmp[lane & 15][(lane >> 4) << 3];
        for (int ks = ksa; ks + 1 < ksb; ks += 2) {
            const short8_t a0 = *(const short8_t*)&arow[ks << 5];
            const short8_t b0 = *(const short8_t*)&wpw[(ks << 9) + (lane << 3)];
            acc0 = __builtin_amdgcn_mfma_f32_16x16x32_bf16(a0, b0, acc0, 0, 0, 0);
            const short8_t a1 = *(const short8_t*)&arow[(ks+1) << 5];
            const short8_t b1 = *(const short8_t*)&wpw[((ks+1) << 9) + (lane << 3)];
            acc1 = __builtin_amdgcn_mfma_f32_16x16x32_bf16(a1, b1, acc1, 0, 0, 0);
        }
        if ((ksb - ksa) & 1) {
            const int ks = ksb - 1;
            const short8_t a0 = *(const short8_t*)&arow[ks << 5];
            const short8_t b0 = *(const short8_t*)&wpw[(ks << 9) + (lane << 3)];
            acc0 = __builtin_amdgcn_mfma_f32_16x16x32_bf16(a0, b0, acc0, 0, 0, 0);
        }
        const int row = (lane >> 4) * 4;
#pragma unroll
        for (int r = 0; r < 4; ++r)
            pm[kh*1024 + (row + r)*64 + (q << 4) + (lane & 15)] = acc0[r] + acc1[r];
    }
    __syncthreads();

    // ============ GRU stage A: x|h interleaved bf16 into a_cmp rows =========
    {
        const float x = fmaxf(embo + pm[w*64 + lane] + pm[1024 + w*64 + lane]
                                   + pm[2048 + w*64 + lane] + pm[3072 + w*64 + lane], 0.f);
        *(unsigned*)&a_cmp[w][lane*2] = pack2(x, hin_reg);
    }
    __syncthreads();

    // ============ GRU stage B: MFMA G[16x256] = [x|h][16x128]*Wgru, 1 T/wave
    {
        short8_t afr[4];
#pragma unroll
        for (int kstep = 0; kstep < 4; ++kstep)
            afr[kstep] = *(const short8_t*)&a_cmp[lane & 15][((lane >> 4) << 3) + (kstep << 5)];

        const unsigned short* wg = ws_us + WGRU_US;
        const float b = ws[B4_OFF + (w << 4) + (lane & 15)];
        f32x4 acc = {b, b, b, b};
#pragma unroll
        for (int kstep = 0; kstep < 4; ++kstep) {
            const short8_t bfr = *(const short8_t*)&wg[(((w << 2) + kstep) << 9) + (lane << 3)];
            acc = __builtin_amdgcn_mfma_f32_16x16x32_bf16(afr[kstep], bfr, acc, 0, 0, 0);
        }
        const int row = (lane >> 4) * 4;
#pragma unroll
        for (int r = 0; r < 4; ++r) GmF[(row + r)*260 + (w << 4) + (lane & 15)] = acc[r];
    }
    __syncthreads();

    // ============ GRU stage C (wave-private): gates + hh ====================
    {
        const float gr = GmF[w*260 + lane];
        const float gz = GmF[w*260 + 64 + lane];
        const float gi = GmF[w*260 + 128 + lane];
        const float gh = GmF[w*260 + 192 + lane];
        const float r = 1.f / (1.f + expf(-gr));
        const float z = 1.f / (1.f + expf(-gz));
        const float t = tanhf(gi + r * gh);
        const float hh = (1.f - z) * t + z * hin_reg;
        a_cmp[w][lane] = to_bf16(hh);
    }
    __syncthreads();

    // ============ vv via MFMA: vv[16x64] = hh[16x64] * Wc[64x64] (waves 0-7)
    if (w < 8) {
        const int q2  = w & 3;
        const int kh2 = w >> 2;               // 0..1
        float* vvp = GmF;                     // [2][16][64] flat, aliases Gm
        const short8_t av = *(const short8_t*)&a_cmp[lane & 15][((lane >> 4) << 3) + (kh2 << 5)];
        const short8_t bv = *(const short8_t*)&ws_us[WVV_US + ((((q2 << 1) + kh2) << 9) + (lane << 3))];
        const float wbv = kh2 ? 0.f : ws[WB_OFF + (q2 << 4) + (lane & 15)];
        f32x4 acc = {wbv, wbv, wbv, wbv};
        acc = __builtin_amdgcn_mfma_f32_16x16x32_bf16(av, bv, acc, 0, 0, 0);
        const int row = (lane >> 4) * 4;
#pragma unroll
        for (int r = 0; r < 4; ++r)
            vvp[kh2*1024 + (row + r)*64 + (q2 << 4) + (lane & 15)] = acc[r];
    }
    __syncthreads();

    // ============ Epilogue (wave-private from here) =========================
    {
        // vv stash
        const float vv = GmF[w*64 + lane] + GmF[1024 + w*64 + lane];
        a_cmp[w][64 + lane] = to_bf16(vv);

        // recompute h_e from staged enemies (stage intact; weights L1-hot)
        {
            const float4 w1a = *(const float4*)(he_w1 + lane*8);
            const float4 w1b = *(const float4*)(he_w1 + lane*8 + 4);
            const float  hb1 = he_b1[lane];
            const float* se  = stg + w*88;
#pragma unroll
            for (int ei = 0; ei < NE_; ei++) {
                const float4 e0 = *(const float4*)(se + ei*8);
                const float4 e1 = *(const float4*)(se + ei*8 + 4);
                float h = hb1;
                h = fmaf(e0.x, w1a.x, h); h = fmaf(e0.y, w1a.y, h);
                h = fmaf(e0.z, w1a.z, h); h = fmaf(e0.w, w1a.w, h);
                h = fmaf(e1.x, w1b.x, h); h = fmaf(e1.y, w1b.y, h);
                h = fmaf(e1.z, w1b.z, h); h = fmaf(e1.w, w1b.w, h);
                a_cmp[w][128 + ei*64 + lane] = to_bf16(fmaxf(h, 0.f));
            }
        }

        // fc2+sn (A = all 16 agents' hh) and q_att (wave-private A)
        short8_t ah[2], bVf[2];
#pragma unroll
        for (int kstep = 0; kstep < 2; ++kstep) {
            ah[kstep]  = *(const short8_t*)&a_cmp[lane & 15][((lane >> 4) << 3) + (kstep << 5)];
            bVf[kstep] = *(const short8_t*)&a_cmp[w][64 + ((lane >> 4) << 3) + (kstep << 5)];
        }
        const float fb = ws[FB_OFF + (lane & 15)];
        f32x4 accF = {fb, fb, fb, fb};
        f32x4 accQ = {0.f, 0.f, 0.f, 0.f};
#pragma unroll
        for (int kstep = 0; kstep < 2; ++kstep) {
            const short8_t bf = *(const short8_t*)&ws_us[WFC2_US + (kstep << 9) + (lane << 3)];
            accF = __builtin_amdgcn_mfma_f32_16x16x32_bf16(ah[kstep], bf, accF, 0, 0, 0);
            const short8_t aA = *(const short8_t*)&a_cmp[w][128 + (lane & 15)*64 + ((lane >> 4) << 3) + (kstep << 5)];
            accQ = __builtin_amdgcn_mfma_f32_16x16x32_bf16(aA, bVf[kstep], accQ, 0, 0, 0);
        }

        // row w of accF: lanes lane>>4 == w>>2, component w&3
        const int rsel = w & 3;
        float fv = accF[0];
        if (rsel == 1) fv = accF[1];
        else if (rsel == 2) fv = accF[2];
        else if (rsel == 3) fv = accF[3];
        const float sn = __shfl(fv, ((w >> 2) << 4) + 6);

        float* o = out + (size_t)n*17;
        if ((lane >> 4) == (w >> 2) && (lane & 15) < 6)
            o[lane & 15] = fv;
        if ((lane & 15) == 0) {
            const int r0 = (lane >> 4) * 4;
#pragma unroll
            for (int r = 0; r < 4; ++r) {
                const int ei = r0 + r;
                if (ei < NE_) o[6 + ei] = accQ[r] + sn;
            }
        }
    }
}

extern "C" void kernel_launch(void* const* d_in, const int* in_sizes, int n_in,
                              void* d_out, int out_size, void* d_ws, size_t ws_size,
                              hipStream_t stream)
{
    const float* own_feats   = (const float*)d_in[0];
    const float* enemy_feats = (const float*)d_in[1];
    const float* ally_feats  = (const float*)d_in[2];
    const float* hidden      = (const float*)d_in[3];
    const int*   agent_idx   = (const int*)d_in[4];
    const int*   last_act    = (const int*)d_in[5];
    const float* fc1_own_w   = (const float*)d_in[6];
    const float* fc1_own_b   = (const float*)d_in[7];
    const float* agent_emb   = (const float*)d_in[8];
    const float* action_emb  = (const float*)d_in[9];
    const float* he_w1       = (const float*)d_in[10];
    const float* he_b1       = (const float*)d_in[11];
    const float* he_w2       = (const float*)d_in[12];
    const float* he_b2       = (const float*)d_in[13];
    const float* ha_w1       = (const float*)d_in[14];
    const float* ha_b1       = (const float*)d_in[15];
    const float* ha_w2       = (const float*)d_in[16];
    const float* ha_b2       = (const float*)d_in[17];
    const float* merge_in_w  = (const float*)d_in[18];
    const float* gru_w_ih    = (const float*)d_in[19];
    const float* gru_w_hh    = (const float*)d_in[20];
    const float* gru_b_ih    = (const float*)d_in[21];
    const float* gru_b_hh    = (const float*)d_in[22];
    const float* fc2_w       = (const float*)d_in[23];
    const float* fc2_b       = (const float*)d_in[24];
    const float* merge_out_w = (const float*)d_in[25];
    float* out = (float*)d_out;
    float* ws  = (float*)d_ws;

    hipLaunchKernelGGL(prep_kernel, dim3(414), dim3(256), 0, stream,
                       fc1_own_w, fc1_own_b, he_w2, he_b2, ha_w2, ha_b2, merge_in_w,
                       gru_w_ih, gru_w_hh, gru_b_ih, gru_b_hh, merge_out_w,
                       fc2_w, fc2_b, ws);
    hipLaunchKernelGGL(main_kernel, dim3(NTOT_/AGB_), dim3(1024), 0, stream,
                       own_feats, enemy_feats, ally_feats, hidden, agent_idx, last_act,
                       agent_emb, action_emb, he_w1, he_b1, ha_w1, ha_b1,
                       ws, out);
}

// Round 18
// 22.689 us; speedup vs baseline: 1.1811x; 1.1811x over previous
//
#include <hip/hip_runtime.h>
#include <hip/hip_bf16.h>
#include <math.h>

// Problem constants
#define BS_    512
#define NA_    10
#define NE_    11
#define NAL_   9
#define H_     64
#define HEADS_ 4
#define EDIM_  8
#define ADIM_  8
#define OWN_   14
#define HYP_   64
#define NTOT_  (BS_*NA_)   // 5120
#define AGB_   8           // agents per block

// ws layout:
//   ushort [0, 67584):        phase2 Wpack[q][ks][fl][j] bf16, K-permuted, own-fc1 folded
//   ushort [67584, 100352):   GRU Wpack[T][kstep][fl][j] bf16, x|h interleaved
//   ushort [100352, 104448):  VV pack[nt(4)][kstep(2)][fl][j] bf16 (Wc[h][col])
//   ushort [104448, 105472):  FC2 pack[kstep(2)][fl][j] bf16 (cols: fc2_w 0..5 | bb | 0)
//   float offsets (1 float = 2 ushorts):
#define WGRU_US   67584
#define WVV_US    100352
#define WFC2_US   104448
#define WB_OFF    52736     // [64]
#define B4_OFF    52800     // [256] gru bias (r | z | i_n | h_n)
#define FB_OFF    53056     // [16]  fc2 bias table: fc2_b 0..5 | cc | 0
#define WS_FLOATS 53072

typedef __attribute__((ext_vector_type(8))) short short8_t;
typedef __attribute__((ext_vector_type(4))) float f32x4;

__device__ __forceinline__ unsigned short to_bf16(float v) {
    unsigned u = __float_as_uint(v);
    u += 0x7fffu + ((u >> 16) & 1u);
    return (unsigned short)(u >> 16);
}
__device__ __forceinline__ unsigned pack2(float lo, float hi) {
    return ((unsigned)to_bf16(hi) << 16) | to_bf16(lo);
}

__global__ __launch_bounds__(256) void prep_kernel(
    const float* __restrict__ fc1_own_w, const float* __restrict__ fc1_own_b,
    const float* __restrict__ he_w2, const float* __restrict__ he_b2,
    const float* __restrict__ ha_w2, const float* __restrict__ ha_b2,
    const float* __restrict__ merge_in_w,
    const float* __restrict__ gru_w_ih, const float* __restrict__ gru_w_hh,
    const float* __restrict__ gru_b_ih, const float* __restrict__ gru_b_hh,
    const float* __restrict__ merge_out_w,
    const float* __restrict__ fc2_w, const float* __restrict__ fc2_b,
    float* __restrict__ ws)
{
    const int tid = blockIdx.x * blockDim.x + threadIdx.x;

    float wo0, wo1, wo2, wo3;
    {
        float e0 = expf(merge_out_w[0]), e1 = expf(merge_out_w[1]);
        float e2 = expf(merge_out_w[2]), e3 = expf(merge_out_w[3]);
        float inv = 1.0f / (e0 + e1 + e2 + e3);
        wo0 = e0*inv; wo1 = e1*inv; wo2 = e2*inv; wo3 = e3*inv;
    }

    if (tid < 65536) {
        // phase-2 Wpack, k<1024: lane-coalesced he/ha_w2 reads (lane = kk).
        const int half = tid >> 15;
        const int t    = tid & 32767;
        const int col  = t >> 9;
        const int idxL = t & 511;
        const int e    = idxL >> 6;
        const int kk   = idxL & 63;
        const float e0 = expf(merge_in_w[col]),       e1 = expf(merge_in_w[64 + col]);
        const float e2 = expf(merge_in_w[128 + col]), e3 = expf(merge_in_w[192 + col]);
        const float inv = 1.0f / (e0 + e1 + e2 + e3);
        const float wi[4] = { e0*inv, e1*inv, e2*inv, e3*inv };
        const float* Wsrc = half ? ha_w2 : he_w2;
        float v = 0.f;
#pragma unroll
        for (int hd = 0; hd < 4; hd++)
            v += wi[hd] * Wsrc[(size_t)(e*256 + hd*64 + col)*64 + kk];
        const int k   = half*512 + kk*8 + e;
        const int ks  = k >> 5, sub = k & 31;
        const int outp = (col >> 4)*16896 + ks*512 + (((sub >> 3) << 4) + (col & 15))*8 + (sub & 7);
        ((unsigned short*)ws)[outp] = to_bf16(v);
    } else if (tid < 67584) {
        // phase-2 Wpack, k = 1024..1055: bias rows + own-fc1 fold
        const int t   = tid - 65536;
        const int col = t >> 5;
        const int io  = t & 31;
        float v = 0.f;
        if (io < 16) {
            const float e0 = expf(merge_in_w[col]),       e1 = expf(merge_in_w[64 + col]);
            const float e2 = expf(merge_in_w[128 + col]), e3 = expf(merge_in_w[192 + col]);
            const float inv = 1.0f / (e0 + e1 + e2 + e3);
            const float wi[4] = { e0*inv, e1*inv, e2*inv, e3*inv };
            const float* Bsrc = (io < 8) ? he_b2 : ha_b2;
            const int e = io & 7;
#pragma unroll
            for (int hd = 0; hd < 4; hd++)
                v += wi[hd] * Bsrc[e*256 + hd*64 + col];
        } else if (io < 30) {
            v = fc1_own_w[col*OWN_ + (io - 16)];
        } else if (io == 30) {
            v = fc1_own_b[col];
        }
        const int outp = (col >> 4)*16896 + 32*512 + (((io >> 3) << 4) + (col & 15))*8 + (io & 7);
        ((unsigned short*)ws)[outp] = to_bf16(v);
    } else if (tid < 100352) {
        // GRU Wpack[T][kstep][fl][j]: k interleaved x|h
        const int t = tid - 67584;
        const int j  = t & 7;
        const int fl = (t >> 3) & 63;
        const int kstep = (t >> 9) & 3;
        const int T  = t >> 11;
        const int k  = kstep*32 + ((fl >> 4) << 3) + j;
        const int kk = k >> 1;
        const bool hside = (k & 1);
        const int c  = T*16 + (fl & 15);
        const int g  = c >> 6;
        const int u  = c & 63;
        float v;
        if (g == 0)      v = hside ? gru_w_hh[u*64 + kk]       : gru_w_ih[u*64 + kk];
        else if (g == 1) v = hside ? gru_w_hh[(64+u)*64 + kk]  : gru_w_ih[(64+u)*64 + kk];
        else if (g == 2) v = hside ? 0.f                        : gru_w_ih[(128+u)*64 + kk];
        else             v = hside ? gru_w_hh[(128+u)*64 + kk] : 0.f;
        ((unsigned short*)ws)[WGRU_US + t] = to_bf16(v);
    } else if (tid < 104448) {
        // VV pack: B[k][col] = Wc[h=k][col]
        const int t = tid - 100352;
        const int j  = t & 7;
        const int fl = (t >> 3) & 63;
        const int kstep = (t >> 9) & 1;
        const int nt = t >> 10;
        const int k  = kstep*32 + ((fl >> 4) << 3) + j;
        const int col = nt*16 + (fl & 15);
        float v = wo0 * he_w2[(2048 + 0*64 + k)*64 + col]
                + wo1 * he_w2[(2048 + 1*64 + k)*64 + col]
                + wo2 * he_w2[(2048 + 2*64 + k)*64 + col]
                + wo3 * he_w2[(2048 + 3*64 + k)*64 + col];
        ((unsigned short*)ws)[WVV_US + t] = to_bf16(v);
    } else if (tid < 105472) {
        // FC2 pack: B[k][col]; col 0..5 = fc2_w[col][k], col 6 = bb[k], else 0
        const int t = tid - 104448;
        const int j  = t & 7;
        const int fl = (t >> 3) & 63;
        const int kstep = t >> 9;
        const int k  = kstep*32 + ((fl >> 4) << 3) + j;
        const int col = fl & 15;
        float v = 0.f;
        if (col < 6)       v = fc2_w[col*64 + k];
        else if (col == 6) v = wo0*he_b2[2048 + 0*64 + k] + wo1*he_b2[2048 + 1*64 + k]
                             + wo2*he_b2[2048 + 2*64 + k] + wo3*he_b2[2048 + 3*64 + k];
        ((unsigned short*)ws)[WFC2_US + t] = to_bf16(v);
    } else if (tid < 105536) {
        const int k = tid - 105472;
        float v = wo0*he_w2[(2304+0)*64 + k] + wo1*he_w2[(2304+1)*64 + k]
                + wo2*he_w2[(2304+2)*64 + k] + wo3*he_w2[(2304+3)*64 + k];
        ws[WB_OFF + k] = v;
    } else if (tid < 105792) {
        const int c = tid - 105536;
        const int g = c >> 6, u = c & 63;
        float v;
        if (g == 0)      v = gru_b_ih[u]       + gru_b_hh[u];
        else if (g == 1) v = gru_b_ih[64 + u]  + gru_b_hh[64 + u];
        else if (g == 2) v = gru_b_ih[128 + u];
        else             v = gru_b_hh[128 + u];
        ws[B4_OFF + c] = v;
    } else if (tid < 105808) {
        const int col = tid - 105792;
        float v = 0.f;
        if (col < 6)       v = fc2_b[col];
        else if (col == 6) v = wo0*he_b2[2304] + wo1*he_b2[2305] + wo2*he_b2[2306] + wo3*he_b2[2307];
        ws[FB_OFF + col] = v;
    }
}

// LDS stage layout (floats): enemy [0,704) ally [704,1280) hidden [1280,1792) own [1792,1904)
#define STG_ALLY 704
#define STG_HID  1280
#define STG_OWN  1792

// a_cmp row stride 1064 us (conflict-free b128 A-reads)
#define AROW_ 1064

__global__ __launch_bounds__(512, 6) void main_kernel(
    const float* __restrict__ own_feats,
    const float* __restrict__ enemy_feats,
    const float* __restrict__ ally_feats,
    const float* __restrict__ hidden_state,
    const int*   __restrict__ agent_idx,
    const int*   __restrict__ last_act,
    const float* __restrict__ agent_emb,
    const float* __restrict__ action_emb,
    const float* __restrict__ he_w1,
    const float* __restrict__ he_b1,
    const float* __restrict__ ha_w1,
    const float* __restrict__ ha_b1,
    const float* __restrict__ ws,
    float* __restrict__ out)
{
    const int tid  = threadIdx.x;
    const int w    = tid >> 6;        // wave id 0..7 == agent slot
    const int lane = tid & 63;
    const int n    = blockIdx.x * AGB_ + w;
    const int q    = w & 3;
    const int kh   = w >> 2;
    const unsigned short* ws_us = (const unsigned short*)ws;

    __shared__ __align__(16) unsigned short a_cmp[AGB_][AROW_]; // 17024 B
    __shared__ __align__(16) float scratch[3104];               // 12416 B
    float* const stg    = scratch;
    float* const GmF    = scratch;          // [8][260]
    float* const pembMF = scratch + 2080;   // [2][8][64]

    // ============ Phase 0: cooperative input staging ========================
    {
        const int n0 = blockIdx.x * AGB_;
        const float4* src = nullptr;
        float* dst = nullptr;
        if (tid < 176)      { src = (const float4*)(enemy_feats + (size_t)n0*88) + tid;         dst = stg + tid*4; }
        else if (tid < 320) { src = (const float4*)(ally_feats + (size_t)n0*72) + (tid-176);    dst = stg + STG_ALLY + (tid-176)*4; }
        else if (tid < 448) { src = (const float4*)(hidden_state + (size_t)n0*64) + (tid-320);  dst = stg + STG_HID + (tid-320)*4; }
        else if (tid < 476) { src = (const float4*)(own_feats + (size_t)n0*14) + (tid-448);     dst = stg + STG_OWN + (tid-448)*4; }
        if (src) *(float4*)dst = *src;
    }
    __syncthreads();

    // ================= Phase 1: per-agent activations (wave = agent) ========
    float h_e[NE_];
    float embo, hin_reg;
    {
        const float4 w1a  = *(const float4*)(he_w1 + lane*8);
        const float4 w1b  = *(const float4*)(he_w1 + lane*8 + 4);
        const float  hb1  = he_b1[lane];
        const float* se = stg + w*88;

        float ps[8] = {0,0,0,0,0,0,0,0};
#pragma unroll
        for (int ei = 0; ei < NE_; ei++) {
            const float4 e0 = *(const float4*)(se + ei*8);
            const float4 e1 = *(const float4*)(se + ei*8 + 4);
            float h = hb1;
            h = fmaf(e0.x, w1a.x, h); h = fmaf(e0.y, w1a.y, h);
            h = fmaf(e0.z, w1a.z, h); h = fmaf(e0.w, w1a.w, h);
            h = fmaf(e1.x, w1b.x, h); h = fmaf(e1.y, w1b.y, h);
            h = fmaf(e1.z, w1b.z, h); h = fmaf(e1.w, w1b.w, h);
            h = fmaxf(h, 0.f);
            h_e[ei] = h;
            ps[0] = fmaf(e0.x, h, ps[0]); ps[1] = fmaf(e0.y, h, ps[1]);
            ps[2] = fmaf(e0.z, h, ps[2]); ps[3] = fmaf(e0.w, h, ps[3]);
            ps[4] = fmaf(e1.x, h, ps[4]); ps[5] = fmaf(e1.y, h, ps[5]);
            ps[6] = fmaf(e1.z, h, ps[6]); ps[7] = fmaf(e1.w, h, ps[7]);
        }
        {
            uint4 pk;
            pk.x = pack2(ps[0], ps[1]); pk.y = pack2(ps[2], ps[3]);
            pk.z = pack2(ps[4], ps[5]); pk.w = pack2(ps[6], ps[7]);
            *(uint4*)&a_cmp[w][lane*8] = pk;
        }

        const float4 wa1a = *(const float4*)(ha_w1 + lane*8);
        const float4 wa1b = *(const float4*)(ha_w1 + lane*8 + 4);
        const float  hba1 = ha_b1[lane];
        const float* sa = stg + STG_ALLY + w*72;
        float pa[8] = {0,0,0,0,0,0,0,0};
#pragma unroll
        for (int ai = 0; ai < NAL_; ai++) {
            const float4 a0 = *(const float4*)(sa + ai*8);
            const float4 a1 = *(const float4*)(sa + ai*8 + 4);
            float h = hba1;
            h = fmaf(a0.x, wa1a.x, h); h = fmaf(a0.y, wa1a.y, h);
            h = fmaf(a0.z, wa1a.z, h); h = fmaf(a0.w, wa1a.w, h);
            h = fmaf(a1.x, wa1b.x, h); h = fmaf(a1.y, wa1b.y, h);
            h = fmaf(a1.z, wa1b.z, h); h = fmaf(a1.w, wa1b.w, h);
            h = fmaxf(h, 0.f);
            pa[0] = fmaf(a0.x, h, pa[0]); pa[1] = fmaf(a0.y, h, pa[1]);
            pa[2] = fmaf(a0.z, h, pa[2]); pa[3] = fmaf(a0.w, h, pa[3]);
            pa[4] = fmaf(a1.x, h, pa[4]); pa[5] = fmaf(a1.y, h, pa[5]);
            pa[6] = fmaf(a1.z, h, pa[6]); pa[7] = fmaf(a1.w, h, pa[7]);
        }
        {
            uint4 pk;
            pk.x = pack2(pa[0], pa[1]); pk.y = pack2(pa[2], pa[3]);
            pk.z = pack2(pa[4], pa[5]); pk.w = pack2(pa[6], pa[7]);
            *(uint4*)&a_cmp[w][512 + lane*8] = pk;
        }

        if (lane < 8) {
            float s = 0.f;
            for (int ei = 0; ei < NE_; ei++) s += se[ei*8 + lane];
            a_cmp[w][1024 + lane] = to_bf16(s);
        } else if (lane < 16) {
            const int p = lane - 8;
            float s = 0.f;
            for (int ai = 0; ai < NAL_; ai++) s += sa[ai*8 + p];
            a_cmp[w][1032 + p] = to_bf16(s);
        } else if (lane < 32) {
            float v;
            if (lane < 30)       v = stg[STG_OWN + w*OWN_ + (lane - 16)];
            else if (lane == 30) v = 1.f;
            else                 v = 0.f;
            a_cmp[w][1024 + lane] = to_bf16(v);
        }

        embo = agent_emb[agent_idx[n]*64 + lane] + action_emb[last_act[n]*64 + lane];
        hin_reg = stg[STG_HID + (w << 6) + lane];
    }
    __syncthreads();

    // ====== Phase 2: MFMA emb[8x64] = A[8x1056]*W, wave=(quad,Khalf) ========
    {
        const int ksa = kh ? 17 : 0;
        const int ksb = kh ? 33 : 17;
        f32x4 acc0 = {0.f, 0.f, 0.f, 0.f};
        f32x4 acc1 = {0.f, 0.f, 0.f, 0.f};
        const unsigned short* wpw = ws_us + ((q * 33) << 9);
        const unsigned short* arow = &a_cmp[lane & 7][(lane >> 4) << 3];
        for (int ks = ksa; ks + 1 < ksb; ks += 2) {
            const short8_t a0 = *(const short8_t*)&arow[ks << 5];
            const short8_t b0 = *(const short8_t*)&wpw[(ks << 9) + (lane << 3)];
            acc0 = __builtin_amdgcn_mfma_f32_16x16x32_bf16(a0, b0, acc0, 0, 0, 0);
            const short8_t a1 = *(const short8_t*)&arow[(ks+1) << 5];
            const short8_t b1 = *(const short8_t*)&wpw[((ks+1) << 9) + (lane << 3)];
            acc1 = __builtin_amdgcn_mfma_f32_16x16x32_bf16(a1, b1, acc1, 0, 0, 0);
        }
        if ((ksb - ksa) & 1) {
            const int ks = ksb - 1;
            const short8_t a0 = *(const short8_t*)&arow[ks << 5];
            const short8_t b0 = *(const short8_t*)&wpw[(ks << 9) + (lane << 3)];
            acc0 = __builtin_amdgcn_mfma_f32_16x16x32_bf16(a0, b0, acc0, 0, 0, 0);
        }
        if (lane < 32) {
            const int row = (lane >> 4) * 4;
#pragma unroll
            for (int r = 0; r < 4; ++r)
                pembMF[kh*512 + (row + r)*64 + (q << 4) + (lane & 15)] = acc0[r] + acc1[r];
        }
    }
    __syncthreads();

    // ============ GRU stage A: x|h interleaved bf16 into a_cmp rows =========
    {
        const float x = fmaxf(embo + pembMF[w*64 + lane] + pembMF[512 + w*64 + lane], 0.f);
        *(unsigned*)&a_cmp[w][lane*2] = pack2(x, hin_reg);
    }
    __syncthreads();

    // ============ GRU stage B: MFMA G[8x256] = [x|h][8x128]*Wgru, 2 T/wave ==
    {
        short8_t afr[4];
#pragma unroll
        for (int kstep = 0; kstep < 4; ++kstep)
            afr[kstep] = *(const short8_t*)&a_cmp[lane & 7][((lane >> 4) << 3) + (kstep << 5)];

        const unsigned short* wg = ws_us + WGRU_US;
#pragma unroll
        for (int tt = 0; tt < 2; ++tt) {
            const int T = (w << 1) + tt;
            const float b = ws[B4_OFF + (T << 4) + (lane & 15)];
            f32x4 acc = {b, b, b, b};
#pragma unroll
            for (int kstep = 0; kstep < 4; ++kstep) {
                const short8_t bfr = *(const short8_t*)&wg[(((T << 2) + kstep) << 9) + (lane << 3)];
                acc = __builtin_amdgcn_mfma_f32_16x16x32_bf16(afr[kstep], bfr, acc, 0, 0, 0);
            }
            if (lane < 32) {
                const int row = (lane >> 4) * 4;
#pragma unroll
                for (int r = 0; r < 4; ++r) GmF[(row + r)*260 + (T << 4) + (lane & 15)] = acc[r];
            }
        }
    }
    __syncthreads();

    // ============ GRU stage C (wave-private): gates + hh ====================
    {
        const float gr = GmF[w*260 + lane];
        const float gz = GmF[w*260 + 64 + lane];
        const float gi = GmF[w*260 + 128 + lane];
        const float gh = GmF[w*260 + 192 + lane];
        const float r = 1.f / (1.f + expf(-gr));
        const float z = 1.f / (1.f + expf(-gz));
        const float t = tanhf(gi + r * gh);
        const float hh = (1.f - z) * t + z * hin_reg;
        a_cmp[w][lane] = to_bf16(hh);      // A-operand for vv / fc2 MFMA
    }
    __syncthreads();

    // ============ vv via MFMA: vv[8x64] = hh[8x64] * Wc[64x64] ==============
    {
        float* vvp = GmF;                  // [2][8][64] flat
        const short8_t av = *(const short8_t*)&a_cmp[lane & 7][((lane >> 4) << 3) + (kh << 5)];
        const short8_t bv = *(const short8_t*)&ws_us[WVV_US + ((((q << 1) + kh) << 9) + (lane << 3))];
        const float wbv = kh ? 0.f : ws[WB_OFF + (q << 4) + (lane & 15)];
        f32x4 acc = {wbv, wbv, wbv, wbv};
        acc = __builtin_amdgcn_mfma_f32_16x16x32_bf16(av, bv, acc, 0, 0, 0);
        if (lane < 32) {
            const int row = (lane >> 4) * 4;
#pragma unroll
            for (int r = 0; r < 4; ++r)
                vvp[kh*512 + (row + r)*64 + (q << 4) + (lane & 15)] = acc[r];
        }
    }
    __syncthreads();

    // ============ Epilogue: q_normal+sn and q_attack via MFMA ===============
    {
        // stash vv (bf16) and h_e (bf16) into dead wave-private a_cmp regions
        const float vv = GmF[w*64 + lane] + GmF[512 + w*64 + lane];
        a_cmp[w][64 + lane] = to_bf16(vv);
#pragma unroll
        for (int ei = 0; ei < NE_; ei++)
            a_cmp[w][128 + ei*64 + lane] = to_bf16(h_e[ei]);
        // wave-private LDS RAW below: lgkmcnt-ordered, no barrier needed

        // fc2+sn: D[8x7] = hh[8x64] * Bfc2[64x16]  (cols 0..5 q_normal, 6 sn)
        const float fb = ws[FB_OFF + (lane & 15)];
        f32x4 accF = {fb, fb, fb, fb};
        f32x4 accQ = {0.f, 0.f, 0.f, 0.f};
#pragma unroll
        for (int kstep = 0; kstep < 2; ++kstep) {
            const short8_t ah = *(const short8_t*)&a_cmp[lane & 7][((lane >> 4) << 3) + (kstep << 5)];
            const short8_t bf = *(const short8_t*)&ws_us[WFC2_US + (kstep << 9) + (lane << 3)];
            accF = __builtin_amdgcn_mfma_f32_16x16x32_bf16(ah, bf, accF, 0, 0, 0);
            // q_att: D[ei][*] = h_e[11x64] * vv_broadcast (rows 11..15 garbage, unread)
            const short8_t aA = *(const short8_t*)&a_cmp[w][128 + (lane & 15)*64 + ((lane >> 4) << 3) + (kstep << 5)];
            const short8_t bV = *(const short8_t*)&a_cmp[w][64 + ((lane >> 4) << 3) + (kstep << 5)];
            accQ = __builtin_amdgcn_mfma_f32_16x16x32_bf16(aA, bV, accQ, 0, 0, 0);
        }

        // row w of accF: lanes with lane>>4 == w>>2, component w&3 (uniform select)
        const int rsel = w & 3;
        float fv = accF[0];
        if (rsel == 1) fv = accF[1];
        else if (rsel == 2) fv = accF[2];
        else if (rsel == 3) fv = accF[3];
        const float sn = __shfl(fv, ((w >> 2) << 4) + 6);

        float* o = out + (size_t)n*17;
        if ((lane >> 4) == (w >> 2) && (lane & 15) < 6)
            o[lane & 15] = fv;
        if ((lane & 15) == 0) {
            const int r0 = (lane >> 4) * 4;
#pragma unroll
            for (int r = 0; r < 4; ++r) {
                const int ei = r0 + r;
                if (ei < NE_) o[6 + ei] = accQ[r] + sn;
            }
        }
    }
}

extern "C" void kernel_launch(void* const* d_in, const int* in_sizes, int n_in,
                              void* d_out, int out_size, void* d_ws, size_t ws_size,
                              hipStream_t stream)
{
    const float* own_feats   = (const float*)d_in[0];
    const float* enemy_feats = (const float*)d_in[1];
    const float* ally_feats  = (const float*)d_in[2];
    const float* hidden      = (const float*)d_in[3];
    const int*   agent_idx   = (const int*)d_in[4];
    const int*   last_act    = (const int*)d_in[5];
    const float* fc1_own_w   = (const float*)d_in[6];
    const float* fc1_own_b   = (const float*)d_in[7];
    const float* agent_emb   = (const float*)d_in[8];
    const float* action_emb  = (const float*)d_in[9];
    const float* he_w1       = (const float*)d_in[10];
    const float* he_b1       = (const float*)d_in[11];
    const float* he_w2       = (const float*)d_in[12];
    const float* he_b2       = (const float*)d_in[13];
    const float* ha_w1       = (const float*)d_in[14];
    const float* ha_b1       = (const float*)d_in[15];
    const float* ha_w2       = (const float*)d_in[16];
    const float* ha_b2       = (const float*)d_in[17];
    const float* merge_in_w  = (const float*)d_in[18];
    const float* gru_w_ih    = (const float*)d_in[19];
    const float* gru_w_hh    = (const float*)d_in[20];
    const float* gru_b_ih    = (const float*)d_in[21];
    const float* gru_b_hh    = (const float*)d_in[22];
    const float* fc2_w       = (const float*)d_in[23];
    const float* fc2_b       = (const float*)d_in[24];
    const float* merge_out_w = (const float*)d_in[25];
    float* out = (float*)d_out;
    float* ws  = (float*)d_ws;

    hipLaunchKernelGGL(prep_kernel, dim3(414), dim3(256), 0, stream,
                       fc1_own_w, fc1_own_b, he_w2, he_b2, ha_w2, ha_b2, merge_in_w,
                       gru_w_ih, gru_w_hh, gru_b_ih, gru_b_hh, merge_out_w,
                       fc2_w, fc2_b, ws);
    hipLaunchKernelGGL(main_kernel, dim3(NTOT_/AGB_), dim3(512), 0, stream,
                       own_feats, enemy_feats, ally_feats, hidden, agent_idx, last_act,
                       agent_emb, action_emb, he_w1, he_b1, ha_w1, ha_b1,
                       ws, out);
}